// Round 4
// baseline (14016.411 us; speedup 1.0000x reference)
//
#include <hip/hip_runtime.h>
#include <math.h>

// PointerNet: B=256, Li=512, Lo=128, C=16, E=128, H=256
// v4: v3's structure (group-local barriers, Whh in VGPRs, broadcast LDS reads,
// decoder Whh-dot hoisted into stage C) with v2's proven fp32 numerics:
//  - enc_proj computed IN-LOOP in fp32 (W1 rows in a 2nd VGPR file), no h_hist
//  - no inline-asm stores anywhere (all cross-WG stores are compiler-visible
//    atomics so barrier waitcnt insertion is sound) + explicit vmcnt drain
//  - logits written with nontemporal stores to keep encp L3-resident

typedef float vf4 __attribute__((ext_vector_type(4)));

__device__ __forceinline__ void ld4_sc1(const vf4* p, vf4& a0, vf4& a1, vf4& a2, vf4& a3) {
  asm volatile(
      "global_load_dwordx4 %0, %4, off sc0 sc1\n\t"
      "global_load_dwordx4 %1, %5, off sc0 sc1\n\t"
      "global_load_dwordx4 %2, %6, off sc0 sc1\n\t"
      "global_load_dwordx4 %3, %7, off sc0 sc1\n\t"
      "s_waitcnt vmcnt(0)"
      : "=&v"(a0), "=&v"(a1), "=&v"(a2), "=&v"(a3)
      : "v"(p), "v"(p + 1), "v"(p + 2), "v"(p + 3)
      : "memory");
}

__device__ __forceinline__ float ld_f32_sc1(const float* p) {
  float v;
  asm volatile("global_load_dword %0, %1, off sc0 sc1\n\ts_waitcnt vmcnt(0)"
               : "=v"(v) : "v"(p) : "memory");
  return v;
}

__device__ __forceinline__ float tanh_fast(float x) {
  float e = __expf(2.0f * x);
  return 1.0f - 2.0f * __builtin_amdgcn_rcpf(e + 1.0f);
}

// Group barrier over the 16 WGs sharing bi (one 64B flag line per group).
// ws poisoned 0xAA -> flags start negative; generations count from 1.
__device__ __forceinline__ void groupbar(int* gf, int myslot, int g) {
  // explicit drain: every wave's global stores complete before its flag/wait
  asm volatile("s_waitcnt vmcnt(0)" ::: "memory");
  __syncthreads();
  if (threadIdx.x == 0)
    __hip_atomic_store(&gf[myslot], g, __ATOMIC_RELAXED, __HIP_MEMORY_SCOPE_AGENT);
  if (threadIdx.x < 64) {
    const int* fp = gf + (threadIdx.x & 15);
    for (;;) {
      int f;
      asm volatile("global_load_dword %0, %1, off sc0 sc1\n\ts_waitcnt vmcnt(0)"
                   : "=v"(f) : "v"(fp) : "memory");
      if (__ballot(f >= g) == ~0ull) break;
      __builtin_amdgcn_s_sleep(1);
    }
  }
  __syncthreads();
}

__device__ __forceinline__ void load_htile(const float* src, float* lds_h_, int tid) {
  int r = tid >> 4;
  int k0 = (tid & 15) << 4;
  vf4 a0, a1, a2, a3;
  ld4_sc1((const vf4*)(src + (r << 8) + k0), a0, a1, a2, a3);
  vf4* dst = (vf4*)(lds_h_ + r * 260 + k0);
  dst[0] = a0; dst[1] = a1; dst[2] = a2; dst[3] = a3;
}

__global__ __launch_bounds__(256, 1) void pointer_net_kernel(
    const float* __restrict__ inputs,  // [256,512,16]
    const float* __restrict__ emb_W,   // [128,16]
    const float* __restrict__ emb_b,   // [128]
    const float* __restrict__ eWih,    // [1024,128]
    const float* __restrict__ eWhh,    // [1024,256]
    const float* __restrict__ eb,      // [1024]
    const float* __restrict__ dWih,    // [1024,128]
    const float* __restrict__ dWhh,    // [1024,256]
    const float* __restrict__ db,      // [1024]
    const float* __restrict__ W1,      // [256,256]
    const float* __restrict__ W2,      // [256,256]
    const float* __restrict__ Vv,      // [256]
    const float* __restrict__ d0,      // [128]
    float* __restrict__ out,           // logits [256,512,128] | pointers [256,128]
    float* __restrict__ encp,          // ws: [256,512,256] fp32
    float* __restrict__ h_buf,         // ws: [2,256,256] fp32 ping-pong
    int* __restrict__ ptr_buf,         // ws: [256]
    int* __restrict__ flags)           // ws: [256]
{
  __shared__ float lds_h[16 * 260];     // h tile (16 b x 256 k, padded)
  __shared__ float lds_part[256 * 17];  // gate partials [((bb*4+g)*4+ks)][sdl]
  __shared__ float lds_pw[64 * 17];     // W1 partials [(bb*4+ks)][sdl]
  __shared__ float lds_wx[2][1024];     // fused input weights enc/dec
  __shared__ float lds_sc[512];
  __shared__ float lds_de[256];
  __shared__ float lds_hr[256];

  const int tid = threadIdx.x;
  // XCD-co-locating swizzle (speed heuristic only; correctness never depends
  // on placement — all cross-WG traffic is sc1/L3-coherent)
  const int B = blockIdx.x;
  const int bi = ((B & 7) << 1) | (B >> 7);   // group id 0..15
  const int dj = (B >> 3) & 15;               // slot in group 0..15
  const int bl = tid >> 4, dl = tid & 15;
  const int b = (bi << 4) + bl;      // cell-role batch row
  const int d = (dj << 4) + dl;      // cell-role hidden dim
  const int b_own = (bi << 4) + dj;  // attention row owned by this WG (same group)
  const int lane = tid & 63;
  const int wv = tid >> 6;
  // slice role: thread = (sdl, sg, sks)
  const int sdl = tid & 15, sg = (tid >> 4) & 3, sks = tid >> 6;
  int* gflags = flags + (bi << 4);

  asm volatile("buffer_inv sc1\n\ts_waitcnt vmcnt(0)" ::: "memory");

  // ---- slice weights: encoder Whh rows + W1 rows into VGPRs ----
  vf4 wreg[16], w1reg[16];
  {
    const float* ws = eWhh + ((size_t)((sg << 8) + (dj << 4) + sdl)) * 256 + (sks << 6);
    const float* w1s = W1 + ((size_t)(dj << 4) + sdl) * 256 + (sks << 6);
#pragma unroll
    for (int j = 0; j < 16; ++j) { wreg[j] = *(const vf4*)(ws + (j << 2));
                                   w1reg[j] = *(const vf4*)(w1s + (j << 2)); }
  }

  // ---- fused input weights (Wih @ emb_W) ----
  for (int idx = tid; idx < 1024; idx += 256) {
    int c = idx >> 6, jj = idx & 63;                  // jj = dl*4+gate
    int j = ((jj & 3) << 8) + (dj << 4) + (jj >> 2);  // gate*256 + dj*16 + dl
    float se = 0.f, sd = 0.f;
    const float* er = eWih + (size_t)j * 128;
    const float* dr = dWih + (size_t)j * 128;
    for (int e = 0; e < 128; ++e) {
      float ew = emb_W[(e << 4) + c];
      se += er[e] * ew;
      sd += dr[e] * ew;
    }
    lds_wx[0][idx] = se;
    lds_wx[1][idx] = sd;
  }
  float benr[4], dber[4], dbemb[4], g0r[4];
  for (int g = 0; g < 4; ++g) {
    int j = (g << 8) + d;
    const float* er = eWih + (size_t)j * 128;
    const float* dr = dWih + (size_t)j * 128;
    float s1 = 0.f, s2 = 0.f, s3 = 0.f;
    for (int e = 0; e < 128; ++e) {
      s1 += er[e] * emb_b[e];
      s2 += dr[e] * emb_b[e];
      s3 += dr[e] * d0[e];
    }
    benr[g] = eb[j] + s1;
    dber[g] = db[j];
    dbemb[g] = s2;
    g0r[g] = s3;
  }
  vf4 v4 = *((const vf4*)Vv + lane);

  float c_reg = 0.0f;
  int gen = 0;

#define SLICE_FMA_GATES()                                                        \
  {                                                                              \
    for (int bb = 0; bb < 16; ++bb) {                                            \
      const float* hb = lds_h + bb * 260 + (sks << 6);                           \
      float acc = 0.f;                                                           \
      _Pragma("unroll")                                                          \
      for (int j = 0; j < 16; ++j) {                                             \
        vf4 h4 = *(const vf4*)(hb + (j << 2));                                   \
        acc += h4.x * wreg[j].x + h4.y * wreg[j].y + h4.z * wreg[j].z +          \
               h4.w * wreg[j].w;                                                 \
      }                                                                          \
      lds_part[((((bb << 2) | sg) << 2) | sks) * 17 + sdl] = acc;                \
    }                                                                            \
  }

#define SLICE_FMA_W1()                                                           \
  {                                                                              \
    for (int q = 0; q < 4; ++q) {                                                \
      int bbw = (q << 2) | sg;                                                   \
      const float* hb = lds_h + bbw * 260 + (sks << 6);                          \
      float acc = 0.f;                                                           \
      _Pragma("unroll")                                                          \
      for (int j = 0; j < 16; ++j) {                                             \
        vf4 h4 = *(const vf4*)(hb + (j << 2));                                   \
        acc += h4.x * w1reg[j].x + h4.y * w1reg[j].y + h4.z * w1reg[j].z +       \
               h4.w * w1reg[j].w;                                                \
      }                                                                          \
      lds_pw[(((bbw << 2) | sks)) * 17 + sdl] = acc;                             \
    }                                                                            \
  }

#define RED_G(g) (lds_part[(((bl << 2) | (g)) << 2) * 17 + dl] +                 \
                  lds_part[((((bl << 2) | (g)) << 2) | 1) * 17 + dl] +           \
                  lds_part[((((bl << 2) | (g)) << 2) | 2) * 17 + dl] +           \
                  lds_part[((((bl << 2) | (g)) << 2) | 3) * 17 + dl])

#define WX_ADD(sel, xp)                                                          \
  {                                                                              \
    for (int c = 0; c < 16; c += 4) {                                            \
      vf4 xv = *(const vf4*)((xp) + c);                                          \
      vf4 wx0 = *(const vf4*)(&lds_wx[sel][((c + 0) << 6) + (dl << 2)]);         \
      vf4 wx1 = *(const vf4*)(&lds_wx[sel][((c + 1) << 6) + (dl << 2)]);         \
      vf4 wx2 = *(const vf4*)(&lds_wx[sel][((c + 2) << 6) + (dl << 2)]);         \
      vf4 wx3 = *(const vf4*)(&lds_wx[sel][((c + 3) << 6) + (dl << 2)]);         \
      a0 += xv.x * wx0.x + xv.y * wx1.x + xv.z * wx2.x + xv.w * wx3.x;           \
      a1 += xv.x * wx0.y + xv.y * wx1.y + xv.z * wx2.y + xv.w * wx3.y;           \
      a2 += xv.x * wx0.z + xv.y * wx1.z + xv.z * wx2.z + xv.w * wx3.z;           \
      a3 += xv.x * wx0.w + xv.y * wx1.w + xv.z * wx2.w + xv.w * wx3.w;           \
    }                                                                            \
  }

  // ============ ENCODER: t=0..512 (1 group-barrier each; 513 total) ============
  // iter t: (t>0) lds_h <- h_t; gate partials + W1 partials; encp row t-1;
  //         (t<512) cell update -> h_{t+1}
  for (int t = 0; t <= 512; ++t) {
    const int pr = t & 1;
    if (t > 0) {
      load_htile(h_buf + pr * 65536 + (bi << 12), lds_h, tid);
      __syncthreads();
      SLICE_FMA_GATES();
      SLICE_FMA_W1();
      __syncthreads();
      float ev = lds_pw[((bl << 2) | 0) * 17 + dl] + lds_pw[((bl << 2) | 1) * 17 + dl]
               + lds_pw[((bl << 2) | 2) * 17 + dl] + lds_pw[((bl << 2) | 3) * 17 + dl];
      __hip_atomic_store(&encp[(((size_t)(b << 9) + (t - 1)) << 8) + d], ev,
                         __ATOMIC_RELAXED, __HIP_MEMORY_SCOPE_AGENT);
    }
    if (t < 512) {
      float a0 = benr[0], a1 = benr[1], a2 = benr[2], a3 = benr[3];
      if (t > 0) { a0 += RED_G(0); a1 += RED_G(1); a2 += RED_G(2); a3 += RED_G(3); }
      const float* xp = inputs + (size_t)(((b << 9) + t) << 4);
      WX_ADD(0, xp);
      float ig = 1.0f / (1.0f + expf(-a0));
      float fg = 1.0f / (1.0f + expf(-a1));
      float gg = tanhf(a2);
      float og = 1.0f / (1.0f + expf(-a3));
      c_reg = fg * c_reg + ig * gg;
      float hn = og * tanhf(c_reg);
      __hip_atomic_store(&h_buf[(pr ^ 1) * 65536 + (b << 8) + d], hn,
                         __ATOMIC_RELAXED, __HIP_MEMORY_SCOPE_AGENT);
    }
    groupbar(gflags, dj, ++gen);
  }

  // ---- decoder slice weights; pre-compute Whh_dec · h_512 partials ----
  {
    const float* ws = dWhh + ((size_t)((sg << 8) + (dj << 4) + sdl)) * 256 + (sks << 6);
#pragma unroll
    for (int j = 0; j < 16; ++j) wreg[j] = *(const vf4*)(ws + (j << 2));
  }
  load_htile(h_buf + 0 + (bi << 12), lds_h, tid);  // h_512 lives in buf 0
  __syncthreads();
  SLICE_FMA_GATES();
  __syncthreads();

  // ============ DECODER: 128 steps, 2 group-barriers each ============
  for (int t = 0; t < 128; ++t) {
    const int nxt = (t & 1) ^ 1;
    // ---- stage A: gates from saved partials + input gather; cell update ----
    {
      float a0 = dber[0] + RED_G(0), a1 = dber[1] + RED_G(1),
            a2 = dber[2] + RED_G(2), a3 = dber[3] + RED_G(3);
      if (t == 0) {
        a0 += g0r[0]; a1 += g0r[1]; a2 += g0r[2]; a3 += g0r[3];
      } else {
        a0 += dbemb[0]; a1 += dbemb[1]; a2 += dbemb[2]; a3 += dbemb[3];
        int pidx = __hip_atomic_load(&ptr_buf[b], __ATOMIC_RELAXED, __HIP_MEMORY_SCOPE_AGENT);
        const float* xp = inputs + (size_t)(((b << 9) + pidx) << 4);
        WX_ADD(1, xp);
      }
      float ig = 1.0f / (1.0f + expf(-a0));
      float fg = 1.0f / (1.0f + expf(-a1));
      float gg = tanhf(a2);
      float og = 1.0f / (1.0f + expf(-a3));
      c_reg = fg * c_reg + ig * gg;
      float hn = og * tanhf(c_reg);
      __hip_atomic_store(&h_buf[nxt * 65536 + (b << 8) + d], hn,
                         __ATOMIC_RELAXED, __HIP_MEMORY_SCOPE_AGENT);
    }
    groupbar(gflags, dj, ++gen);

    // ---- stage C: Whh·h partials (for t+1) + W2 dot + scores + argmax ----
    load_htile(h_buf + nxt * 65536 + (bi << 12), lds_h, tid);
    lds_hr[tid] = ld_f32_sc1(&h_buf[nxt * 65536 + (b_own << 8) + tid]);
    __syncthreads();
    SLICE_FMA_GATES();
    {
      float a = 0.0f;
      const float* w2r = W2 + (size_t)tid * 256;
      for (int k = 0; k < 256; k += 4) {
        vf4 h4 = *(const vf4*)(lds_hr + k);
        vf4 q = *(const vf4*)(w2r + k);
        a += h4.x * q.x + h4.y * q.y + h4.z * q.z + h4.w * q.w;
      }
      lds_de[tid] = a;
    }
    __syncthreads();
    {
      vf4 d4 = *((const vf4*)lds_de + lane);
      // plain cached reads: encp written once (sc1 write-through) during the
      // encoder, read-only afterwards; entry buffer_inv purged poison copies.
      const float* bse = encp + ((size_t)b_own << 17) + (wv << 8);
      vf4 A[8], Bv[8];
#pragma unroll
      for (int j = 0; j < 8; ++j)
        A[j] = *((const vf4*)(bse + ((size_t)j << 10)) + lane);
      for (int ch = 0; ch < 16; ++ch) {
        if (ch < 15) {
#pragma unroll
          for (int j = 0; j < 8; ++j)
            Bv[j] = *((const vf4*)(bse + ((size_t)((ch + 1) * 8 + j) << 10)) + lane);
        }
#pragma unroll
        for (int j = 0; j < 8; ++j) {
          int li = wv + (((ch << 3) + j) << 2);
          vf4 e4 = A[j];
          float s = v4.x * tanh_fast(e4.x + d4.x)
                  + v4.y * tanh_fast(e4.y + d4.y)
                  + v4.z * tanh_fast(e4.z + d4.z)
                  + v4.w * tanh_fast(e4.w + d4.w);
#pragma unroll
          for (int off = 32; off; off >>= 1) s += __shfl_down(s, off);
          if (lane == 0) lds_sc[li] = s;
        }
#pragma unroll
        for (int j = 0; j < 8; ++j) A[j] = Bv[j];
      }
      __syncthreads();

      // logits scatter — nontemporal so the 256MB output stream doesn't evict
      // encp from L3
      for (int i = tid; i < 512; i += 256)
        __builtin_nontemporal_store(lds_sc[i], &out[(size_t)(((b_own << 9) + i) << 7) + t]);

      // argmax, first-index tie-break (np.argmax semantics)
      if (tid < 64) {
        float bs = -3.402823466e38f;
        int bix = 0;
        for (int i = 0; i < 8; ++i) {
          int idx = (i << 6) + tid;
          float s = lds_sc[idx];
          if (s > bs || (s == bs && idx < bix)) { bs = s; bix = idx; }
        }
#pragma unroll
        for (int off = 32; off; off >>= 1) {
          float os = __shfl_down(bs, off);
          int oi = __shfl_down(bix, off);
          if (os > bs || (os == bs && oi < bix)) { bs = os; bix = oi; }
        }
        if (tid == 0) {
          __hip_atomic_store(&ptr_buf[b_own], bix, __ATOMIC_RELAXED, __HIP_MEMORY_SCOPE_AGENT);
          __builtin_nontemporal_store((float)bix, &out[(size_t)16777216 + (b_own << 7) + t]);
        }
      }
    }
    groupbar(gflags, dj, ++gen);
  }
#undef SLICE_FMA_GATES
#undef SLICE_FMA_W1
#undef RED_G
#undef WX_ADD
}

extern "C" void kernel_launch(void* const* d_in, const int* in_sizes, int n_in,
                              void* d_out, int out_size, void* d_ws, size_t ws_size,
                              hipStream_t stream) {
  (void)in_sizes; (void)n_in; (void)out_size;
  const float* inputs = (const float*)d_in[0];
  const float* emb_W  = (const float*)d_in[1];
  const float* emb_b  = (const float*)d_in[2];
  const float* eWih   = (const float*)d_in[3];
  const float* eWhh   = (const float*)d_in[4];
  const float* eb     = (const float*)d_in[5];
  const float* dWih   = (const float*)d_in[6];
  const float* dWhh   = (const float*)d_in[7];
  const float* db     = (const float*)d_in[8];
  const float* W1     = (const float*)d_in[9];
  const float* W2     = (const float*)d_in[10];
  const float* Vv     = (const float*)d_in[11];
  const float* d0     = (const float*)d_in[12];

  float* out = (float*)d_out;
  // ws: encp [256*512*256]f | h_buf [2*256*256]f | ptr [256] | flags [256]
  float* encp  = (float*)d_ws;
  float* h_buf = encp + 33554432;
  int*   ptrb  = (int*)(h_buf + 131072);
  int*   flags = ptrb + 256;

  size_t need = (size_t)(33554432 + 131072) * 4 + 512 * 4;
  if (ws_size < need) return;  // fail cleanly rather than OOB

  hipLaunchKernelGGL(pointer_net_kernel, dim3(256), dim3(256), 0, stream,
                     inputs, emb_W, emb_b, eWih, eWhh, eb, dWih, dWhh, db,
                     W1, W2, Vv, d0, out, encp, h_buf, ptrb, flags);
}

// Round 5
// 7799.709 us; speedup vs baseline: 1.7970x; 1.7970x over previous
//
#include <hip/hip_runtime.h>
#include <math.h>

// PointerNet: B=256, Li=512, Lo=128, C=16, E=128, H=256
// v5: 512 thr/WG (2 waves/SIMD); weight-slice reuse R=5 (4 gates + W1 per
// thread) cutting LDS read volume ~4x; forward-only ring sync (depth-4 h ring,
// monotone flags, producer never waits); decoder = ONE h-exchange per step
// (ptr rides in a packed flag word, overlapped with SLICE); fp32 throughout.

typedef float vf4 __attribute__((ext_vector_type(4)));

__device__ __forceinline__ float dot4(vf4 a, vf4 b) {
  return a.x * b.x + a.y * b.y + a.z * b.z + a.w * b.w;
}

__device__ __forceinline__ float tanh_fast(float x) {
  float e = __expf(2.0f * x);
  return 1.0f - 2.0f * __builtin_amdgcn_rcpf(e + 1.0f);
}

#define AL(p) __hip_atomic_load((p), __ATOMIC_RELAXED, __HIP_MEMORY_SCOPE_AGENT)
#define AS(p, v) __hip_atomic_store((p), (v), __ATOMIC_RELAXED, __HIP_MEMORY_SCOPE_AGENT)

__global__ __launch_bounds__(512, 2) void pointer_net_kernel(
    const float* __restrict__ inputs,  // [256,512,16]
    const float* __restrict__ emb_W,   // [128,16]
    const float* __restrict__ emb_b,   // [128]
    const float* __restrict__ eWih,    // [1024,128]
    const float* __restrict__ eWhh,    // [1024,256]
    const float* __restrict__ eb,      // [1024]
    const float* __restrict__ dWih,    // [1024,128]
    const float* __restrict__ dWhh,    // [1024,256]
    const float* __restrict__ db,      // [1024]
    const float* __restrict__ W1,      // [256,256]
    const float* __restrict__ W2,      // [256,256]
    const float* __restrict__ Vv,      // [256]
    const float* __restrict__ d0,      // [128]
    float* __restrict__ out,           // logits [256,512,128] | pointers [256,128]
    float* __restrict__ encp,          // ws: [256,512,256] fp32
    float* __restrict__ ring,          // ws: [16 groups][4 slots][16 rows][256]
    int* __restrict__ hflags,          // ws: [16][16] (one 64B line per group)
    unsigned int* __restrict__ pflags) // ws: [16][16] packed (j<<16)|ptr
{
  __shared__ float lds_h[16 * 260];     // h tile, padded rows
  __shared__ float lds_part[256 * 68];  // gate partials [bb*16+ks][sdl*4+g]
  __shared__ float lds_pw[256 * 17];    // W1 partials  [bb*16+ks][sdl]
  __shared__ float lds_wx[2][1024];     // fused input weights enc/dec
  __shared__ float lds_sc[512];
  __shared__ float lds_de[512];         // W2-dot halves [hf][256]

  const int tid = threadIdx.x;
  const int B = blockIdx.x;
  // XCD-co-locating swizzle (speed-only): all 16 WGs of a group share B%8
  const int bi = ((B & 7) << 1) | (B >> 7);  // group 0..15
  const int dj = (B >> 3) & 15;              // slot in group
  const int bl = tid >> 4, dl = tid & 15;    // cell role (tid<256)
  const int b = (bi << 4) + bl;
  const int d = (dj << 4) + dl;
  const int b_own = (bi << 4) + dj;          // attention row this WG owns
  const int lane = tid & 63;
  const int wv = tid >> 6;                   // wave 0..7
  // slice role: (sdl, sks, sbh)
  const int sdl = tid & 15, sks = (tid >> 4) & 15, sbh8 = (tid >> 8) << 3;
  // tile-load role
  const int trow = tid >> 5, tcol = (tid & 31) << 3;

  int* hfg = hflags + (bi << 4);
  unsigned int* pfg = pflags + (bi << 4);
  float* ring_g = ring + ((size_t)bi << 14);  // 4 slots * 4096

  asm volatile("buffer_inv sc1\n\ts_waitcnt vmcnt(0)" ::: "memory");

  // ---- weight slices into VGPRs: 4 gate rows + W1 row, k-slice sks*16 ----
  vf4 wreg[16], w1reg[4];
  {
    const int k0 = sks << 4;
#pragma unroll
    for (int g = 0; g < 4; ++g) {
      const float* wr = eWhh + ((size_t)((g << 8) + (dj << 4) + sdl)) * 256 + k0;
#pragma unroll
      for (int q = 0; q < 4; ++q) wreg[(g << 2) + q] = *(const vf4*)(wr + (q << 2));
    }
    const float* w1r = W1 + ((size_t)(dj << 4) + sdl) * 256 + k0;
#pragma unroll
    for (int q = 0; q < 4; ++q) w1reg[q] = *(const vf4*)(w1r + (q << 2));
  }

  // ---- fused input weights (Wih @ emb_W) for this WG's 16 dims ----
  for (int idx = tid; idx < 1024; idx += 512) {
    int c = idx >> 6, jj = idx & 63;                  // jj = dl*4+gate
    int j = ((jj & 3) << 8) + (dj << 4) + (jj >> 2);  // gate*256 + dj*16 + dl
    float se = 0.f, sd = 0.f;
    const float* er = eWih + (size_t)j * 128;
    const float* dr = dWih + (size_t)j * 128;
    for (int e = 0; e < 128; ++e) {
      float ew = emb_W[(e << 4) + c];
      se += er[e] * ew;
      sd += dr[e] * ew;
    }
    lds_wx[0][idx] = se;
    lds_wx[1][idx] = sd;
  }
  float benr[4] = {0, 0, 0, 0}, dber[4] = {0, 0, 0, 0},
        dbemb[4] = {0, 0, 0, 0}, g0r[4] = {0, 0, 0, 0};
  if (tid < 256) {
    for (int g = 0; g < 4; ++g) {
      int j = (g << 8) + d;
      const float* er = eWih + (size_t)j * 128;
      const float* dr = dWih + (size_t)j * 128;
      float s1 = 0.f, s2 = 0.f, s3 = 0.f;
      for (int e = 0; e < 128; ++e) {
        s1 += er[e] * emb_b[e];
        s2 += dr[e] * emb_b[e];
        s3 += dr[e] * d0[e];
      }
      benr[g] = eb[j] + s1;
      dber[g] = db[j];
      dbemb[g] = s2;
      g0r[g] = s3;
    }
  }
  vf4 v4a = *((const vf4*)Vv + lane);
  float c_reg = 0.0f;
  __syncthreads();  // lds_wx ready

#define POLL_H(u)                                                                \
  if (tid < 64) {                                                                \
    const int* fp = hfg + (tid & 15);                                            \
    for (;;) {                                                                   \
      int f;                                                                     \
      asm volatile("global_load_dword %0, %1, off sc0 sc1\n\ts_waitcnt vmcnt(0)" \
                   : "=v"(f) : "v"(fp) : "memory");                              \
      if (__ballot(f >= (u)) == ~0ull) break;                                    \
      __builtin_amdgcn_s_sleep(1);                                               \
    }                                                                            \
  }                                                                              \
  __syncthreads();

#define LOAD_TILE(slot)                                                          \
  {                                                                              \
    float* src = ring_g + ((size_t)(slot) << 12) + (trow << 8) + tcol;           \
    float v[8];                                                                  \
    _Pragma("unroll") for (int i = 0; i < 8; ++i) v[i] = AL(src + i);            \
    float* dst = lds_h + trow * 260 + tcol;                                      \
    _Pragma("unroll") for (int i = 0; i < 8; ++i) dst[i] = v[i];                 \
  }                                                                              \
  __syncthreads();

#define SLICE(do_gates, do_w1)                                                   \
  for (int bb = sbh8; bb < sbh8 + 8; ++bb) {                                     \
    const float* hb = lds_h + bb * 260 + (sks << 4);                             \
    vf4 h0 = *(const vf4*)(hb);                                                  \
    vf4 h1 = *(const vf4*)(hb + 4);                                              \
    vf4 h2 = *(const vf4*)(hb + 8);                                              \
    vf4 h3 = *(const vf4*)(hb + 12);                                             \
    int r = (bb << 4) + sks;                                                     \
    if (do_gates) {                                                              \
      vf4 s;                                                                     \
      s.x = dot4(h0, wreg[0]) + dot4(h1, wreg[1]) + dot4(h2, wreg[2]) +          \
            dot4(h3, wreg[3]);                                                   \
      s.y = dot4(h0, wreg[4]) + dot4(h1, wreg[5]) + dot4(h2, wreg[6]) +          \
            dot4(h3, wreg[7]);                                                   \
      s.z = dot4(h0, wreg[8]) + dot4(h1, wreg[9]) + dot4(h2, wreg[10]) +         \
            dot4(h3, wreg[11]);                                                  \
      s.w = dot4(h0, wreg[12]) + dot4(h1, wreg[13]) + dot4(h2, wreg[14]) +       \
            dot4(h3, wreg[15]);                                                  \
      *(vf4*)(lds_part + r * 68 + (sdl << 2)) = s;                               \
    }                                                                            \
    if (do_w1) {                                                                 \
      lds_pw[r * 17 + sdl] = dot4(h0, w1reg[0]) + dot4(h1, w1reg[1]) +           \
                             dot4(h2, w1reg[2]) + dot4(h3, w1reg[3]);            \
    }                                                                            \
  }

#define RED_GATES(a0, a1, a2, a3)                                                \
  _Pragma("unroll") for (int ks = 0; ks < 16; ++ks) {                            \
    vf4 p = *(const vf4*)(lds_part + ((bl << 4) + ks) * 68 + (dl << 2));         \
    a0 += p.x; a1 += p.y; a2 += p.z; a3 += p.w;                                  \
  }

#define WX_ADD(sel, xp, a0, a1, a2, a3)                                          \
  for (int c = 0; c < 16; c += 4) {                                              \
    vf4 xv = *(const vf4*)((xp) + c);                                            \
    vf4 wx0 = *(const vf4*)(&lds_wx[sel][((c + 0) << 6) + (dl << 2)]);           \
    vf4 wx1 = *(const vf4*)(&lds_wx[sel][((c + 1) << 6) + (dl << 2)]);           \
    vf4 wx2 = *(const vf4*)(&lds_wx[sel][((c + 2) << 6) + (dl << 2)]);           \
    vf4 wx3 = *(const vf4*)(&lds_wx[sel][((c + 3) << 6) + (dl << 2)]);           \
    a0 += xv.x * wx0.x + xv.y * wx1.x + xv.z * wx2.x + xv.w * wx3.x;             \
    a1 += xv.x * wx0.y + xv.y * wx1.y + xv.z * wx2.y + xv.w * wx3.y;             \
    a2 += xv.x * wx0.z + xv.y * wx1.z + xv.z * wx2.z + xv.w * wx3.z;             \
    a3 += xv.x * wx0.w + xv.y * wx1.w + xv.z * wx2.w + xv.w * wx3.w;             \
  }

#define ACT_AND_PUBLISH(a0, a1, a2, a3, slot)                                    \
  {                                                                              \
    float ig = 1.0f / (1.0f + expf(-(a0)));                                      \
    float fg = 1.0f / (1.0f + expf(-(a1)));                                      \
    float gg = tanhf(a2);                                                        \
    float og = 1.0f / (1.0f + expf(-(a3)));                                      \
    c_reg = fg * c_reg + ig * gg;                                                \
    float hn = og * tanhf(c_reg);                                                \
    AS(ring_g + ((size_t)(slot) << 12) + (bl << 8) + d, hn);                     \
  }

  // =================== ENCODER t = 0..511 ===================
  for (int t = 0; t < 512; ++t) {
    float a0 = benr[0], a1 = benr[1], a2 = benr[2], a3 = benr[3];
    if (tid < 256) {  // input-weight term first (independent of tile)
      const float* xp = inputs + (size_t)(((b << 9) + t) << 4);
      WX_ADD(0, xp, a0, a1, a2, a3);
    }
    if (t > 0) {
      POLL_H(t);
      LOAD_TILE(t & 3);
      SLICE(1, 1);
      __syncthreads();
    }
    if (tid < 256) {
      if (t > 0) { RED_GATES(a0, a1, a2, a3); }
      ACT_AND_PUBLISH(a0, a1, a2, a3, (t + 1) & 3);
    }
    asm volatile("s_waitcnt vmcnt(0)" ::: "memory");
    __syncthreads();
    if (tid == 0) AS(hfg + dj, t + 1);
    if (t > 0 && tid < 256) {  // encp row t-1, off the critical path
      float ev = 0.f;
#pragma unroll
      for (int ks = 0; ks < 16; ++ks) ev += lds_pw[((bl << 4) + ks) * 17 + dl];
      AS(encp + (((size_t)((b << 9) + (t - 1))) << 8) + d, ev);
    }
  }

  // =================== EPILOGUE: tile h_512, encp row 511, swap weights ======
  POLL_H(512);
  LOAD_TILE(0);  // 512 & 3 == 0
  SLICE(0, 1);
  __syncthreads();
  if (tid < 256) {
    float ev = 0.f;
#pragma unroll
    for (int ks = 0; ks < 16; ++ks) ev += lds_pw[((bl << 4) + ks) * 17 + dl];
    AS(encp + (((size_t)((b << 9) + 511)) << 8) + d, ev);
  }
  {  // decoder recurrent weights
    const int k0 = sks << 4;
#pragma unroll
    for (int g = 0; g < 4; ++g) {
      const float* wr = dWhh + ((size_t)((g << 8) + (dj << 4) + sdl)) * 256 + k0;
#pragma unroll
      for (int q = 0; q < 4; ++q) wreg[(g << 2) + q] = *(const vf4*)(wr + (q << 2));
    }
  }
  SLICE(1, 0);  // gate partials for decoder j=0 (tile h_512 still in LDS)
  __syncthreads();

  // =================== DECODER j = 0..127 (one h-exchange per step) ==========
  for (int j = 0; j < 128; ++j) {
    const int u = 513 + j;
    // ---- gates + cell (partials already in lds_part) ----
    if (tid < 256) {
      float a0 = dber[0], a1 = dber[1], a2 = dber[2], a3 = dber[3];
      RED_GATES(a0, a1, a2, a3);
      if (j == 0) {
        a0 += g0r[0]; a1 += g0r[1]; a2 += g0r[2]; a3 += g0r[3];
      } else {
        a0 += dbemb[0]; a1 += dbemb[1]; a2 += dbemb[2]; a3 += dbemb[3];
        unsigned int pf;
        for (;;) {  // ptr published by peer's scores of iter j-1 (overlapped)
          pf = AL(pfg + bl);
          if ((pf >> 16) == (unsigned int)(j - 1)) break;
          __builtin_amdgcn_s_sleep(1);
        }
        const float* xp = inputs + (size_t)(((b << 9) + (int)(pf & 0xffff)) << 4);
        WX_ADD(1, xp, a0, a1, a2, a3);
      }
      ACT_AND_PUBLISH(a0, a1, a2, a3, u & 3);
    }
    asm volatile("s_waitcnt vmcnt(0)" ::: "memory");
    __syncthreads();
    if (tid == 0) AS(hfg + dj, u);

    // ---- exchange h^{(j+1)} ----
    POLL_H(u);
    LOAD_TILE(u & 3);

    // ---- dec_term = own row (dj) @ W2^T, split over 512 threads ----
    {
      const int d2 = tid & 255, hf = tid >> 8;
      const float* hrow = lds_h + dj * 260 + (hf << 7);
      const float* w2r = W2 + (size_t)d2 * 256 + (hf << 7);
      float a = 0.f;
      for (int k = 0; k < 128; k += 4) {
        vf4 h4 = *(const vf4*)(hrow + k);
        vf4 q = *(const vf4*)(w2r + k);
        a += dot4(h4, q);
      }
      lds_de[(hf << 8) + d2] = a;
    }
    __syncthreads();

    // ---- scores + argmax (all 8 waves; 64 li per wave) ----
    {
      vf4 p0 = *((const vf4*)lds_de + lane);
      vf4 p1 = *((const vf4*)(lds_de + 256) + lane);
      vf4 d4; d4.x = p0.x + p1.x; d4.y = p0.y + p1.y;
              d4.z = p0.z + p1.z; d4.w = p0.w + p1.w;
      const vf4* bse = (const vf4*)(encp + ((size_t)b_own << 17));
      vf4 A[8], Bv[8];
#pragma unroll
      for (int jj = 0; jj < 8; ++jj)
        A[jj] = bse[((size_t)(wv + (jj << 3)) << 6) + lane];
      for (int ch = 0; ch < 8; ++ch) {
        if (ch < 7) {
#pragma unroll
          for (int jj = 0; jj < 8; ++jj)
            Bv[jj] = bse[((size_t)(wv + (((ch + 1) * 8 + jj) << 3)) << 6) + lane];
        }
#pragma unroll
        for (int jj = 0; jj < 8; ++jj) {
          int li = wv + (((ch << 3) + jj) << 3);
          vf4 e4 = A[jj];
          float s = v4a.x * tanh_fast(e4.x + d4.x)
                  + v4a.y * tanh_fast(e4.y + d4.y)
                  + v4a.z * tanh_fast(e4.z + d4.z)
                  + v4a.w * tanh_fast(e4.w + d4.w);
#pragma unroll
          for (int off = 32; off; off >>= 1) s += __shfl_down(s, off);
          if (lane == 0) lds_sc[li] = s;
        }
#pragma unroll
        for (int jj = 0; jj < 8; ++jj) A[jj] = Bv[jj];
      }
      __syncthreads();

      // logits out (one per thread, nontemporal)
      __builtin_nontemporal_store(lds_sc[tid],
          &out[(size_t)(((b_own << 9) + tid) << 7) + j]);

      // argmax (wave 0), first-index tie-break = np.argmax
      if (tid < 64) {
        float bs = -3.402823466e38f;
        int bix = 0;
        for (int i = 0; i < 8; ++i) {
          int idx = (i << 6) + tid;
          float s = lds_sc[idx];
          if (s > bs || (s == bs && idx < bix)) { bs = s; bix = idx; }
        }
#pragma unroll
        for (int off = 32; off; off >>= 1) {
          float os = __shfl_down(bs, off);
          int oi = __shfl_down(bix, off);
          if (os > bs || (os == bs && oi < bix)) { bs = os; bix = oi; }
        }
        if (tid == 0) {
          AS(pfg + dj, ((unsigned int)j << 16) | (unsigned int)bix);
          __builtin_nontemporal_store((float)bix,
              &out[(size_t)16777216 + (b_own << 7) + j]);
        }
      }
    }

    // ---- gate partials for iter j+1 (after ptr publish: off critical path) --
    if (j < 127) {
      SLICE(1, 0);
      __syncthreads();
    }
  }
#undef POLL_H
#undef LOAD_TILE
#undef SLICE
#undef RED_GATES
#undef WX_ADD
#undef ACT_AND_PUBLISH
}

extern "C" void kernel_launch(void* const* d_in, const int* in_sizes, int n_in,
                              void* d_out, int out_size, void* d_ws, size_t ws_size,
                              hipStream_t stream) {
  (void)in_sizes; (void)n_in; (void)out_size;
  const float* inputs = (const float*)d_in[0];
  const float* emb_W  = (const float*)d_in[1];
  const float* emb_b  = (const float*)d_in[2];
  const float* eWih   = (const float*)d_in[3];
  const float* eWhh   = (const float*)d_in[4];
  const float* eb     = (const float*)d_in[5];
  const float* dWih   = (const float*)d_in[6];
  const float* dWhh   = (const float*)d_in[7];
  const float* db     = (const float*)d_in[8];
  const float* W1     = (const float*)d_in[9];
  const float* W2     = (const float*)d_in[10];
  const float* Vv     = (const float*)d_in[11];
  const float* d0     = (const float*)d_in[12];

  float* out = (float*)d_out;
  // ws: encp [256*512*256] | ring [16*4*16*256] | hflags [256] | pflags [256]
  float* encp   = (float*)d_ws;
  float* ring   = encp + 33554432;
  int*   hflags = (int*)(ring + 262144);
  unsigned int* pflags = (unsigned int*)(hflags + 256);

  size_t need = (size_t)(33554432 + 262144 + 512) * 4;
  if (ws_size < need) return;  // fail cleanly rather than OOB

  hipLaunchKernelGGL(pointer_net_kernel, dim3(256), dim3(512), 0, stream,
                     inputs, emb_W, emb_b, eWih, eWhh, eb, dWih, dWhh, db,
                     W1, W2, Vv, d0, out, encp, ring, hflags, pflags);
}

// Round 6
// 7516.843 us; speedup vs baseline: 1.8647x; 1.0376x over previous
//
#include <hip/hip_runtime.h>
#include <math.h>

// PointerNet: B=256, Li=512, Lo=128, C=16, E=128, H=256
// v6 = v5 + software-pipelined h-exchange: each group's 16 independent batch
// rows split into halves (A=rows 0-7, B=8-15) with separate flag lines; the
// poll for half X(t) executes one half-phase after X(t) was published, hiding
// the L3 round trip behind the other half's compute. Ring tile loads are
// vectorized (1 vf4 asm load/thread per half). Decoder unchanged except
// vectorized full-tile load and early encp prefetch before the W2 dot.

typedef float vf4 __attribute__((ext_vector_type(4)));

__device__ __forceinline__ float dot4(vf4 a, vf4 b) {
  return a.x * b.x + a.y * b.y + a.z * b.z + a.w * b.w;
}

__device__ __forceinline__ float tanh_fast(float x) {
  float e = __expf(2.0f * x);
  return 1.0f - 2.0f * __builtin_amdgcn_rcpf(e + 1.0f);
}

__device__ __forceinline__ vf4 ld1_sc1(const vf4* p) {
  vf4 v;
  asm volatile("global_load_dwordx4 %0, %1, off sc0 sc1\n\ts_waitcnt vmcnt(0)"
               : "=v"(v) : "v"(p) : "memory");
  return v;
}

__device__ __forceinline__ void ld2_sc1(const vf4* p0, const vf4* p1, vf4& v0, vf4& v1) {
  asm volatile(
      "global_load_dwordx4 %0, %2, off sc0 sc1\n\t"
      "global_load_dwordx4 %1, %3, off sc0 sc1\n\t"
      "s_waitcnt vmcnt(0)"
      : "=&v"(v0), "=&v"(v1) : "v"(p0), "v"(p1) : "memory");
}

#define AL(p) __hip_atomic_load((p), __ATOMIC_RELAXED, __HIP_MEMORY_SCOPE_AGENT)
#define AS(p, v) __hip_atomic_store((p), (v), __ATOMIC_RELAXED, __HIP_MEMORY_SCOPE_AGENT)
#define DRAIN() asm volatile("s_waitcnt vmcnt(0)" ::: "memory")

__global__ __launch_bounds__(512, 2) void pointer_net_kernel(
    const float* __restrict__ inputs,  // [256,512,16]
    const float* __restrict__ emb_W,   // [128,16]
    const float* __restrict__ emb_b,   // [128]
    const float* __restrict__ eWih,    // [1024,128]
    const float* __restrict__ eWhh,    // [1024,256]
    const float* __restrict__ eb,      // [1024]
    const float* __restrict__ dWih,    // [1024,128]
    const float* __restrict__ dWhh,    // [1024,256]
    const float* __restrict__ db,      // [1024]
    const float* __restrict__ W1,      // [256,256]
    const float* __restrict__ W2,      // [256,256]
    const float* __restrict__ Vv,      // [256]
    const float* __restrict__ d0,      // [128]
    float* __restrict__ out,           // logits [256,512,128] | pointers [256,128]
    float* __restrict__ encp,          // ws: [256,512,256] fp32
    float* __restrict__ ring,          // ws: [16 groups][4 slots][16 rows][256]
    int* __restrict__ hflags,          // ws: [16 groups][2 halves][16]
    unsigned int* __restrict__ pflags) // ws: [16][16] packed (j<<16)|ptr
{
  __shared__ float lds_h[16 * 260];     // h tile, padded rows
  __shared__ float lds_part[256 * 68];  // gate partials [bb*16+ks][sdl*4+g]
  __shared__ float lds_pw[256 * 17];    // W1 partials  [bb*16+ks][sdl]
  __shared__ float lds_wx[2][1024];     // fused input weights enc/dec
  __shared__ float lds_sc[512];
  __shared__ float lds_de[512];         // W2-dot halves [hf][256]

  const int tid = threadIdx.x;
  const int B = blockIdx.x;
  // XCD-co-locating swizzle (speed-only)
  const int bi = ((B & 7) << 1) | (B >> 7);  // group 0..15
  const int dj = (B >> 3) & 15;              // slot in group
  const int bl = tid >> 4, dl = tid & 15;    // cell role (tid<256)
  const int b = (bi << 4) + bl;
  const int d = (dj << 4) + dl;
  const int b_own = (bi << 4) + dj;
  const int lane = tid & 63;
  const int wv = tid >> 6;
  // slice roles
  const int sdl = tid & 15, sks = (tid >> 4) & 15;
  const int sb4 = (tid >> 8) << 2;   // 4-bb span within a half
  const int sbh8 = (tid >> 8) << 3;  // 8-bb span for full-tile slices

  int* fgA = hflags + (bi << 5);
  int* fgB = fgA + 16;
  unsigned int* pfg = pflags + (bi << 4);
  float* ring_g = ring + ((size_t)bi << 14);

  asm volatile("buffer_inv sc1\n\ts_waitcnt vmcnt(0)" ::: "memory");

  // ---- weight slices into VGPRs: 4 gate rows + W1 row, k-slice sks*16 ----
  vf4 wreg[16], w1reg[4];
  {
    const int k0 = sks << 4;
#pragma unroll
    for (int g = 0; g < 4; ++g) {
      const float* wr = eWhh + ((size_t)((g << 8) + (dj << 4) + sdl)) * 256 + k0;
#pragma unroll
      for (int q = 0; q < 4; ++q) wreg[(g << 2) + q] = *(const vf4*)(wr + (q << 2));
    }
    const float* w1r = W1 + ((size_t)(dj << 4) + sdl) * 256 + k0;
#pragma unroll
    for (int q = 0; q < 4; ++q) w1reg[q] = *(const vf4*)(w1r + (q << 2));
  }

  // ---- fused input weights (Wih @ emb_W) for this WG's 16 dims ----
  for (int idx = tid; idx < 1024; idx += 512) {
    int c = idx >> 6, jj = idx & 63;
    int j = ((jj & 3) << 8) + (dj << 4) + (jj >> 2);
    float se = 0.f, sd = 0.f;
    const float* er = eWih + (size_t)j * 128;
    const float* dr = dWih + (size_t)j * 128;
    for (int e = 0; e < 128; ++e) {
      float ew = emb_W[(e << 4) + c];
      se += er[e] * ew;
      sd += dr[e] * ew;
    }
    lds_wx[0][idx] = se;
    lds_wx[1][idx] = sd;
  }
  float benr[4] = {0, 0, 0, 0}, dber[4] = {0, 0, 0, 0},
        dbemb[4] = {0, 0, 0, 0}, g0r[4] = {0, 0, 0, 0};
  if (tid < 256) {
    for (int g = 0; g < 4; ++g) {
      int j = (g << 8) + d;
      const float* er = eWih + (size_t)j * 128;
      const float* dr = dWih + (size_t)j * 128;
      float s1 = 0.f, s2 = 0.f, s3 = 0.f;
      for (int e = 0; e < 128; ++e) {
        s1 += er[e] * emb_b[e];
        s2 += dr[e] * emb_b[e];
        s3 += dr[e] * d0[e];
      }
      benr[g] = eb[j] + s1;
      dber[g] = db[j];
      dbemb[g] = s2;
      g0r[g] = s3;
    }
  }
  vf4 v4a = *((const vf4*)Vv + lane);
  float c_reg = 0.0f;
  __syncthreads();

#define POLL(fb, u)                                                              \
  if (tid < 64) {                                                                \
    const int* fp = (fb) + (tid & 15);                                           \
    for (;;) {                                                                   \
      int f;                                                                     \
      asm volatile("global_load_dword %0, %1, off sc0 sc1\n\ts_waitcnt vmcnt(0)" \
                   : "=v"(f) : "v"(fp) : "memory");                              \
      if (__ballot(f >= (u)) == ~0ull) break;                                    \
      __builtin_amdgcn_s_sleep(1);                                               \
    }                                                                            \
  }                                                                              \
  __syncthreads();

#define LOAD_HALF(slot, half)                                                    \
  {                                                                              \
    int grow = ((half) << 3) + (tid >> 6);                                       \
    int col = (tid & 63) << 2;                                                   \
    vf4 v = ld1_sc1((const vf4*)(ring_g + ((size_t)(slot) << 12) + (grow << 8) + col)); \
    *(vf4*)(lds_h + grow * 260 + col) = v;                                       \
  }                                                                              \
  __syncthreads();

#define LOAD_FULL(slot)                                                          \
  {                                                                              \
    int r0 = tid >> 6, col = (tid & 63) << 2;                                    \
    const float* base = ring_g + ((size_t)(slot) << 12);                         \
    vf4 v0, v1;                                                                  \
    ld2_sc1((const vf4*)(base + (r0 << 8) + col),                                \
            (const vf4*)(base + ((r0 + 8) << 8) + col), v0, v1);                 \
    *(vf4*)(lds_h + r0 * 260 + col) = v0;                                        \
    *(vf4*)(lds_h + (r0 + 8) * 260 + col) = v1;                                  \
  }                                                                              \
  __syncthreads();

#define SLICE_BODY(bb, do_g, do_w)                                               \
  {                                                                              \
    const float* hb = lds_h + (bb)*260 + (sks << 4);                             \
    vf4 h0 = *(const vf4*)(hb);                                                  \
    vf4 h1 = *(const vf4*)(hb + 4);                                              \
    vf4 h2 = *(const vf4*)(hb + 8);                                              \
    vf4 h3 = *(const vf4*)(hb + 12);                                             \
    int r = ((bb) << 4) + sks;                                                   \
    if (do_g) {                                                                  \
      vf4 s;                                                                     \
      s.x = dot4(h0, wreg[0]) + dot4(h1, wreg[1]) + dot4(h2, wreg[2]) +          \
            dot4(h3, wreg[3]);                                                   \
      s.y = dot4(h0, wreg[4]) + dot4(h1, wreg[5]) + dot4(h2, wreg[6]) +          \
            dot4(h3, wreg[7]);                                                   \
      s.z = dot4(h0, wreg[8]) + dot4(h1, wreg[9]) + dot4(h2, wreg[10]) +         \
            dot4(h3, wreg[11]);                                                  \
      s.w = dot4(h0, wreg[12]) + dot4(h1, wreg[13]) + dot4(h2, wreg[14]) +       \
            dot4(h3, wreg[15]);                                                  \
      *(vf4*)(lds_part + r * 68 + (sdl << 2)) = s;                               \
    }                                                                            \
    if (do_w) {                                                                  \
      lds_pw[r * 17 + sdl] = dot4(h0, w1reg[0]) + dot4(h1, w1reg[1]) +           \
                             dot4(h2, w1reg[2]) + dot4(h3, w1reg[3]);            \
    }                                                                            \
  }

#define SLICE_HALF(half, do_g, do_w)                                             \
  for (int q = 0; q < 4; ++q) SLICE_BODY(((half) << 3) + sb4 + q, do_g, do_w)

#define SLICE_FULL(do_g, do_w)                                                   \
  for (int q = 0; q < 8; ++q) SLICE_BODY(sbh8 + q, do_g, do_w)

#define RED_GATES(a0, a1, a2, a3)                                                \
  _Pragma("unroll") for (int ks = 0; ks < 16; ++ks) {                            \
    vf4 p = *(const vf4*)(lds_part + ((bl << 4) + ks) * 68 + (dl << 2));         \
    a0 += p.x; a1 += p.y; a2 += p.z; a3 += p.w;                                  \
  }

#define WX_ADD(sel, xp, a0, a1, a2, a3)                                          \
  for (int c = 0; c < 16; c += 4) {                                              \
    vf4 xv = *(const vf4*)((xp) + c);                                            \
    vf4 wx0 = *(const vf4*)(&lds_wx[sel][((c + 0) << 6) + (dl << 2)]);           \
    vf4 wx1 = *(const vf4*)(&lds_wx[sel][((c + 1) << 6) + (dl << 2)]);           \
    vf4 wx2 = *(const vf4*)(&lds_wx[sel][((c + 2) << 6) + (dl << 2)]);           \
    vf4 wx3 = *(const vf4*)(&lds_wx[sel][((c + 3) << 6) + (dl << 2)]);           \
    a0 += xv.x * wx0.x + xv.y * wx1.x + xv.z * wx2.x + xv.w * wx3.x;             \
    a1 += xv.x * wx0.y + xv.y * wx1.y + xv.z * wx2.y + xv.w * wx3.y;             \
    a2 += xv.x * wx0.z + xv.y * wx1.z + xv.z * wx2.z + xv.w * wx3.z;             \
    a3 += xv.x * wx0.w + xv.y * wx1.w + xv.z * wx2.w + xv.w * wx3.w;             \
  }

#define ACT_PUB(a0, a1, a2, a3, slot)                                            \
  {                                                                              \
    float ig = 1.0f / (1.0f + expf(-(a0)));                                      \
    float fg = 1.0f / (1.0f + expf(-(a1)));                                      \
    float gg = tanhf(a2);                                                        \
    float og = 1.0f / (1.0f + expf(-(a3)));                                      \
    c_reg = fg * c_reg + ig * gg;                                                \
    float hn = og * tanhf(c_reg);                                                \
    AS(ring_g + ((size_t)(slot) << 12) + (bl << 8) + d, hn);                     \
  }

  // =================== ENCODER t=0 (no tile) ===================
  {
    if (tid < 256) {
      float a0 = benr[0], a1 = benr[1], a2 = benr[2], a3 = benr[3];
      const float* xp = inputs + (size_t)((b << 9) << 4);
      WX_ADD(0, xp, a0, a1, a2, a3);
      ACT_PUB(a0, a1, a2, a3, 1);
    }
    DRAIN();
    __syncthreads();
    if (tid == 0) { AS(fgA + dj, 1); AS(fgB + dj, 1); }
  }

  // =================== ENCODER t=1..511, pipelined halves ===================
  for (int t = 1; t < 512; ++t) {
    float ax0 = 0.f, ax1 = 0.f, ax2 = 0.f, ax3 = 0.f;
    if (tid < 256) {
      ax0 = benr[0]; ax1 = benr[1]; ax2 = benr[2]; ax3 = benr[3];
      const float* xp = inputs + (size_t)(((b << 9) + t) << 4);
      WX_ADD(0, xp, ax0, ax1, ax2, ax3);
    }
    // ---- half A ----
    POLL(fgA, t);
    LOAD_HALF(t & 3, 0);
    SLICE_HALF(0, 1, 1);
    __syncthreads();
    if (tid < 128) {  // cells of rows 0-7
      RED_GATES(ax0, ax1, ax2, ax3);
      ACT_PUB(ax0, ax1, ax2, ax3, (t + 1) & 3);
    }
    DRAIN();
    __syncthreads();
    if (tid == 0) AS(fgA + dj, t + 1);
    if (tid < 128) {
      float ev = 0.f;
#pragma unroll
      for (int ks = 0; ks < 16; ++ks) ev += lds_pw[((bl << 4) + ks) * 17 + dl];
      AS(encp + (((size_t)((b << 9) + (t - 1))) << 8) + d, ev);
    }
    // ---- half B ----
    POLL(fgB, t);
    LOAD_HALF(t & 3, 1);
    SLICE_HALF(1, 1, 1);
    __syncthreads();
    if (tid >= 128 && tid < 256) {  // cells of rows 8-15
      RED_GATES(ax0, ax1, ax2, ax3);
      ACT_PUB(ax0, ax1, ax2, ax3, (t + 1) & 3);
    }
    DRAIN();
    __syncthreads();
    if (tid == 0) AS(fgB + dj, t + 1);
    if (tid >= 128 && tid < 256) {
      float ev = 0.f;
#pragma unroll
      for (int ks = 0; ks < 16; ++ks) ev += lds_pw[((bl << 4) + ks) * 17 + dl];
      AS(encp + (((size_t)((b << 9) + (t - 1))) << 8) + d, ev);
    }
  }

  // =================== boundary: h_512 tile, encp row 511, dec weights =======
  POLL(fgA, 512);
  POLL(fgB, 512);
  LOAD_FULL(0);  // 512 & 3 == 0
  SLICE_FULL(0, 1);
  __syncthreads();
  if (tid < 256) {
    float ev = 0.f;
#pragma unroll
    for (int ks = 0; ks < 16; ++ks) ev += lds_pw[((bl << 4) + ks) * 17 + dl];
    AS(encp + (((size_t)((b << 9) + 511)) << 8) + d, ev);
  }
  {
    const int k0 = sks << 4;
#pragma unroll
    for (int g = 0; g < 4; ++g) {
      const float* wr = dWhh + ((size_t)((g << 8) + (dj << 4) + sdl)) * 256 + k0;
#pragma unroll
      for (int q = 0; q < 4; ++q) wreg[(g << 2) + q] = *(const vf4*)(wr + (q << 2));
    }
  }
  SLICE_FULL(1, 0);  // gate partials for decoder j=0
  __syncthreads();

  // =================== DECODER j = 0..127 ===================
  for (int j = 0; j < 128; ++j) {
    const int u = 513 + j;
    // ---- stage A: gates from saved partials; cell update; publish ----
    if (tid < 256) {
      float a0 = dber[0], a1 = dber[1], a2 = dber[2], a3 = dber[3];
      RED_GATES(a0, a1, a2, a3);
      if (j == 0) {
        a0 += g0r[0]; a1 += g0r[1]; a2 += g0r[2]; a3 += g0r[3];
      } else {
        a0 += dbemb[0]; a1 += dbemb[1]; a2 += dbemb[2]; a3 += dbemb[3];
        unsigned int pf;
        for (;;) {
          pf = AL(pfg + bl);
          if ((pf >> 16) == (unsigned int)(j - 1)) break;
          __builtin_amdgcn_s_sleep(1);
        }
        const float* xp = inputs + (size_t)(((b << 9) + (int)(pf & 0xffff)) << 4);
        WX_ADD(1, xp, a0, a1, a2, a3);
      }
      ACT_PUB(a0, a1, a2, a3, u & 3);
    }
    DRAIN();
    __syncthreads();
    if (tid == 0) AS(fgA + dj, u);

    POLL(fgA, u);
    LOAD_FULL(u & 3);

    // early encp prefetch (independent of h) — overlaps the W2 dot
    const vf4* bse = (const vf4*)(encp + ((size_t)b_own << 17));
    vf4 A[8], Bv[8];
#pragma unroll
    for (int jj = 0; jj < 8; ++jj)
      A[jj] = bse[((size_t)(wv + (jj << 3)) << 6) + lane];

    // ---- dec_term = row dj @ W2^T, split over 512 threads ----
    {
      const int d2 = tid & 255, hf = tid >> 8;
      const float* hrow = lds_h + dj * 260 + (hf << 7);
      const float* w2r = W2 + (size_t)d2 * 256 + (hf << 7);
      float a = 0.f;
      for (int k = 0; k < 128; k += 4) {
        vf4 h4 = *(const vf4*)(hrow + k);
        vf4 q = *(const vf4*)(w2r + k);
        a += dot4(h4, q);
      }
      lds_de[(hf << 8) + d2] = a;
    }
    __syncthreads();

    // ---- scores + argmax ----
    {
      vf4 p0 = *((const vf4*)lds_de + lane);
      vf4 p1 = *((const vf4*)(lds_de + 256) + lane);
      vf4 d4; d4.x = p0.x + p1.x; d4.y = p0.y + p1.y;
              d4.z = p0.z + p1.z; d4.w = p0.w + p1.w;
      for (int ch = 0; ch < 8; ++ch) {
        if (ch < 7) {
#pragma unroll
          for (int jj = 0; jj < 8; ++jj)
            Bv[jj] = bse[((size_t)(wv + (((ch + 1) * 8 + jj) << 3)) << 6) + lane];
        }
#pragma unroll
        for (int jj = 0; jj < 8; ++jj) {
          int li = wv + (((ch << 3) + jj) << 3);
          vf4 e4 = A[jj];
          float s = v4a.x * tanh_fast(e4.x + d4.x)
                  + v4a.y * tanh_fast(e4.y + d4.y)
                  + v4a.z * tanh_fast(e4.z + d4.z)
                  + v4a.w * tanh_fast(e4.w + d4.w);
#pragma unroll
          for (int off = 32; off; off >>= 1) s += __shfl_down(s, off);
          if (lane == 0) lds_sc[li] = s;
        }
#pragma unroll
        for (int jj = 0; jj < 8; ++jj) A[jj] = Bv[jj];
      }
      __syncthreads();

      __builtin_nontemporal_store(lds_sc[tid],
          &out[(size_t)(((b_own << 9) + tid) << 7) + j]);

      if (tid < 64) {
        float bs = -3.402823466e38f;
        int bix = 0;
        for (int i = 0; i < 8; ++i) {
          int idx = (i << 6) + tid;
          float s = lds_sc[idx];
          if (s > bs || (s == bs && idx < bix)) { bs = s; bix = idx; }
        }
#pragma unroll
        for (int off = 32; off; off >>= 1) {
          float os = __shfl_down(bs, off);
          int oi = __shfl_down(bix, off);
          if (os > bs || (os == bs && oi < bix)) { bs = os; bix = oi; }
        }
        if (tid == 0) {
          AS(pfg + dj, ((unsigned int)j << 16) | (unsigned int)bix);
          __builtin_nontemporal_store((float)bix,
              &out[(size_t)16777216 + (b_own << 7) + j]);
        }
      }
    }

    // ---- gate partials for j+1 (after ptr publish: off critical path) ----
    if (j < 127) {
      SLICE_FULL(1, 0);
      __syncthreads();
    }
  }
#undef POLL
#undef LOAD_HALF
#undef LOAD_FULL
#undef SLICE_BODY
#undef SLICE_HALF
#undef SLICE_FULL
#undef RED_GATES
#undef WX_ADD
#undef ACT_PUB
}

extern "C" void kernel_launch(void* const* d_in, const int* in_sizes, int n_in,
                              void* d_out, int out_size, void* d_ws, size_t ws_size,
                              hipStream_t stream) {
  (void)in_sizes; (void)n_in; (void)out_size;
  const float* inputs = (const float*)d_in[0];
  const float* emb_W  = (const float*)d_in[1];
  const float* emb_b  = (const float*)d_in[2];
  const float* eWih   = (const float*)d_in[3];
  const float* eWhh   = (const float*)d_in[4];
  const float* eb     = (const float*)d_in[5];
  const float* dWih   = (const float*)d_in[6];
  const float* dWhh   = (const float*)d_in[7];
  const float* db     = (const float*)d_in[8];
  const float* W1     = (const float*)d_in[9];
  const float* W2     = (const float*)d_in[10];
  const float* Vv     = (const float*)d_in[11];
  const float* d0     = (const float*)d_in[12];

  float* out = (float*)d_out;
  // ws: encp [256*512*256] | ring [16*4*16*256] | hflags [512] | pflags [256]
  float* encp   = (float*)d_ws;
  float* ring   = encp + 33554432;
  int*   hflags = (int*)(ring + 262144);
  unsigned int* pflags = (unsigned int*)(hflags + 512);

  size_t need = (size_t)(33554432 + 262144 + 768) * 4;
  if (ws_size < need) return;  // fail cleanly rather than OOB

  hipLaunchKernelGGL(pointer_net_kernel, dim3(256), dim3(512), 0, stream,
                     inputs, emb_W, emb_b, eWih, eWhh, eb, dWih, dWhh, db,
                     W1, W2, Vv, d0, out, encp, ring, hflags, pflags);
}